// Round 6
// baseline (4916.151 us; speedup 1.0000x reference)
//
#include <hip/hip_runtime.h>
#include <math.h>

#define S_DIM 2048
#define H_DIM 512
#define V_DIM 50000
#define K_DIM 512
#define WINN 11
#define GRU_G 32

typedef __attribute__((ext_vector_type(4))) float f32x4;
typedef __attribute__((ext_vector_type(2))) float f32x2;
typedef __attribute__((ext_vector_type(8))) __bf16 bf16x8;
typedef __attribute__((ext_vector_type(4))) unsigned int u32x4;

__device__ __forceinline__ unsigned int f2bf(float f) {
  union { float f; unsigned int u; } v; v.f = f;
  return (v.u + 0x7fffu + ((v.u >> 16) & 1u)) >> 16;
}
__device__ __forceinline__ unsigned int pack2(float a, float b) {
  return f2bf(a) | (f2bf(b) << 16);
}
// coherent (device-scope) 16B load: polls two adjacent (val,tag) words in
// ONE fabric message. sc0 sc1 = gfx950 coherence flags (bypass stale caches).
__device__ __forceinline__ u32x4 ld_quad(const unsigned long long* p) {
  u32x4 r;
  asm volatile("global_load_dwordx4 %0, %1, off sc0 sc1\n\ts_waitcnt vmcnt(0)"
               : "=v"(r) : "v"(p) : "memory");
  return r;
}

// ---------------- zero init (tagged h exchange buffer + lse accumulators) ----------------
__global__ void k_zero(int* p, int n) {
  int i = blockIdx.x * 256 + threadIdx.x;
  if (i < n) p[i] = 0;
}

// ---------------- fp32 [rows][512] -> bf16 swizzled [tile][kt][q][m=128][8] ----------------
__global__ void k_swizzle(const float* __restrict__ src, unsigned short* __restrict__ dst,
                          int rows_valid, int nchunks) {
  int c = blockIdx.x * 256 + threadIdx.x;
  if (c >= nchunks) return;
  int vt  = c >> 13;          // tile of 128 rows
  int m   = (c >> 6) & 127;   // row within tile
  int ktq = c & 63;           // 8-elem chunk along k (k = 8*ktq)
  int v = vt * 128 + m;
  f32x4 a = {0, 0, 0, 0}, b = {0, 0, 0, 0};
  if (v < rows_valid) {
    const float* s = src + (size_t)v * K_DIM + ktq * 8;
    a = *(const f32x4*)s;
    b = *(const f32x4*)(s + 4);
  }
  u32x4 pk;
  pk.x = pack2(a.x, a.y); pk.y = pack2(a.z, a.w);
  pk.z = pack2(b.x, b.y); pk.w = pack2(b.z, b.w);
  int kt = ktq >> 2, q = ktq & 3;
  int cd = vt * 8192 + kt * 512 + q * 128 + m;
  *(u32x4*)(dst + (size_t)cd * 8) = pk;
}

// ---------------- gather emb[loc] -> bf16 swizzled A ----------------
__global__ void k_gather(const float* __restrict__ emb, const int* __restrict__ loc,
                         unsigned short* __restrict__ dst) {
  int c = blockIdx.x * 256 + threadIdx.x;    // 16*128*64 = 131072 chunks
  int st  = c >> 13;
  int m   = (c >> 6) & 127;
  int ktq = c & 63;
  int s = st * 128 + m;
  int l = loc[s];
  const float* sp = emb + (size_t)l * K_DIM + ktq * 8;
  f32x4 a = *(const f32x4*)sp;
  f32x4 b = *(const f32x4*)(sp + 4);
  u32x4 pk;
  pk.x = pack2(a.x, a.y); pk.y = pack2(a.z, a.w);
  pk.z = pack2(b.x, b.y); pk.w = pack2(b.z, b.w);
  int kt = ktq >> 2, q = ktq & 3;
  int cd = st * 8192 + kt * 512 + q * 128 + m;
  *(u32x4*)(dst + (size_t)cd * 8) = pk;
}

// ---------------- bf16 MFMA GEMM: C[m][n] = sum_k A[m][k]*B[n][k] + bias[n] ----------------
// A,B pre-swizzled [tile128][kt16][q4][row128][8]. Block=256 (4 waves, 2x2 of 64x64).
// If lse_acc != nullptr, also accumulates sum_n exp(C[m][n]) into lse_acc[m]
// (wave-reduced across the 16-lane col group, one atomicAdd per group).
__global__ __launch_bounds__(256) void k_gemm(const unsigned short* __restrict__ A,
                                              const unsigned short* __restrict__ B,
                                              const float* __restrict__ bias,
                                              float* __restrict__ C, int ldc, int nvalid,
                                              float* lse_acc) {
  __shared__ __align__(16) unsigned short Als[4096];
  __shared__ __align__(16) unsigned short Bls[4096];
  int t = threadIdx.x;
  int ntile = blockIdx.x, mtile = blockIdx.y;
  const unsigned short* Ab = A + (size_t)mtile * 65536;
  const unsigned short* Bb = B + (size_t)ntile * 65536;
  int wid = t >> 6, lane = t & 63;
  int qm = wid >> 1, qn = wid & 1;
  int l15 = lane & 15, q4 = lane >> 4;
  f32x4 acc[4][4];
#pragma unroll
  for (int i = 0; i < 4; i++)
#pragma unroll
    for (int j = 0; j < 4; j++) acc[i][j] = (f32x4){0, 0, 0, 0};

  for (int kt = 0; kt < 16; ++kt) {
    __syncthreads();
    ((u32x4*)Als)[t]       = ((const u32x4*)(Ab + kt * 4096))[t];
    ((u32x4*)Als)[t + 256] = ((const u32x4*)(Ab + kt * 4096))[t + 256];
    ((u32x4*)Bls)[t]       = ((const u32x4*)(Bb + kt * 4096))[t];
    ((u32x4*)Bls)[t + 256] = ((const u32x4*)(Bb + kt * 4096))[t + 256];
    __syncthreads();
    bf16x8 af[4], bfr[4];
#pragma unroll
    for (int i = 0; i < 4; i++)
      af[i] = *(const bf16x8*)(&Als[(q4 * 128 + qm * 64 + i * 16 + l15) * 8]);
#pragma unroll
    for (int j = 0; j < 4; j++)
      bfr[j] = *(const bf16x8*)(&Bls[(q4 * 128 + qn * 64 + j * 16 + l15) * 8]);
#pragma unroll
    for (int i = 0; i < 4; i++)
#pragma unroll
      for (int j = 0; j < 4; j++)
        acc[i][j] = __builtin_amdgcn_mfma_f32_16x16x32_bf16(af[i], bfr[j], acc[i][j], 0, 0, 0);
  }

  int m0 = mtile * 128 + qm * 64;
  int n0 = ntile * 128 + qn * 64;
  float bv[4];
#pragma unroll
  for (int j = 0; j < 4; j++) {
    int n = n0 + j * 16 + l15;
    bv[j] = (n < nvalid) ? bias[n] : 0.f;
  }
#pragma unroll
  for (int i = 0; i < 4; i++) {
#pragma unroll
    for (int e = 0; e < 4; e++) {
      int r = m0 + i * 16 + q4 * 4 + e;
      float rs = 0.f;
#pragma unroll
      for (int j = 0; j < 4; j++) {
        int n = n0 + j * 16 + l15;
        if (n < nvalid) {
          float y = acc[i][j][e] + bv[j];
          C[(size_t)r * ldc + n] = y;
          rs += expf(y);
        }
      }
      if (lse_acc) {
        rs += __shfl_xor(rs, 1, 64);
        rs += __shfl_xor(rs, 2, 64);
        rs += __shfl_xor(rs, 4, 64);
        rs += __shfl_xor(rs, 8, 64);
        if (l15 == 0) atomicAdd(&lse_acc[r], rs);
      }
    }
  }
}

// ---------------- persistent GRU scan: 32 WGs x 256 threads ----------------
// Exchange: each h column = one relaxed 64-bit word (low32 = float bits,
// high32 = step tag), parity double-buffered. Poll: thread t issues ONE
// coherent 16B load covering cols {2t, 2t+1} -> 4096 messages/step total
// (message count is the proven cost driver: 32768 msgs regressed, 16384
// regressed, 8192 = previous best; now 4096).
// Thread map: col = t>>4 (16 cols/WG), kq = t&15 (32-elem k slice). Each
// thread computes ALL 3 gate dot-slices for its column (W: 24 f32x4 = 96
// VGPR). After shfl_xor reduce over the 16 slice lanes, the kq==0 lane
// holds (r,z,n) -> computes gates + publishes directly. NO hg_l, ONE
// barrier per step.
// Race-freedom with one barrier: step s+2 stages into buf[s&1] (same as
// step s). To reach staging of s+2 a thread passed B(s+1); B(s+1) requires
// all threads staged s+1, which happens only after they finished their
// step-s LDS reads (dot precedes publish precedes poll(s+1) precedes
// stage(s+1)). h_pairs slot reuse (tag s+2 over tag s) is safe for the
// same reason.
// LDS staged/read through f32x4-chunk XOR swizzle (j ^ ((j>>3)&7)):
// read worst case 2-way (free). Staging = one ds_write_b64 per thread.
__global__ __launch_bounds__(256, 1) void k_gru(const float* __restrict__ W_hh,
                                                const float* __restrict__ b_hh,
                                                const float* __restrict__ xg,
                                                unsigned long long* h_pairs,
                                                float* __restrict__ out_gru) {
  __shared__ __align__(16) float h_lds[2][512];
  int wg = blockIdx.x;
  int t = threadIdx.x;
  int cg = t >> 4;            // column 0..15 within WG
  int kq = t & 15;            // 32-elem k slice
  int col = wg * 16 + cg;
  bool pub = (kq == 0);
  f32x4 wr[3][8];             // W_hh[3 gates][32-elem slice] for this col
  float bh0, bh1, bh2;
#pragma unroll
  for (int gate = 0; gate < 3; gate++) {
    int grow = gate * 512 + col;
    const float* wsrc = W_hh + (size_t)grow * K_DIM + kq * 32;
#pragma unroll
    for (int v = 0; v < 8; v++) wr[gate][v] = *(const f32x4*)(wsrc + v * 4);
  }
  bh0 = b_hh[col]; bh1 = b_hh[512 + col]; bh2 = b_hh[1024 + col];
  float ho = 0.f;             // publisher's running h; h0 = 0
  // staging swizzle: this thread's 16B covers cols {2t,2t+1} = logical
  // chunk j = t>>1, floats (t&1)*2 .. +1 within it
  int j = t >> 1;
  int pj = j ^ ((j >> 3) & 7);
  int stoff = pj * 4 + (t & 1) * 2;

  for (int s = 0; s < S_DIM; ++s) {
    unsigned su = (unsigned)s;
    // gate inputs: independent of h, issued before the poll to hide latency
    float xr = 0.f, xz = 0.f, xn = 0.f;
    if (pub) {
      const float* xrow = xg + (size_t)s * 1536;
      xr = xrow[col]; xz = xrow[512 + col]; xn = xrow[1024 + col];
    }

    // single 16B coherent poll of cols {2t, 2t+1}
    const unsigned long long* p = h_pairs + (size_t)(s & 1) * 512 + t * 2;
    u32x4 q = ld_quad(p);
    while (q.y != su || q.w != su) q = ld_quad(p);
    union { unsigned u; float f; } a0, a1;
    a0.u = q.x; a1.u = q.z;
    float* hb = h_lds[s & 1];
    *(f32x2*)(&hb[stoff]) = (f32x2){a0.f, a1.f};
    __syncthreads();

    // dot: 3 gates x 32-elem slice, h chunk shared across gates in regs
    float p0 = 0.f, p1 = 0.f, p2 = 0.f;
    const f32x4* h4 = (const f32x4*)hb;
#pragma unroll
    for (int v = 0; v < 8; v++) {
      f32x4 hv = h4[(kq * 8 + v) ^ (kq & 7)];
      p0 += wr[0][v].x * hv.x + wr[0][v].y * hv.y + wr[0][v].z * hv.z + wr[0][v].w * hv.w;
      p1 += wr[1][v].x * hv.x + wr[1][v].y * hv.y + wr[1][v].z * hv.z + wr[1][v].w * hv.w;
      p2 += wr[2][v].x * hv.x + wr[2][v].y * hv.y + wr[2][v].z * hv.z + wr[2][v].w * hv.w;
    }
    // reduce over the 16 slice lanes (within 16-lane groups of the wave)
    p0 += __shfl_xor(p0, 1, 64); p1 += __shfl_xor(p1, 1, 64); p2 += __shfl_xor(p2, 1, 64);
    p0 += __shfl_xor(p0, 2, 64); p1 += __shfl_xor(p1, 2, 64); p2 += __shfl_xor(p2, 2, 64);
    p0 += __shfl_xor(p0, 4, 64); p1 += __shfl_xor(p1, 4, 64); p2 += __shfl_xor(p2, 4, 64);
    p0 += __shfl_xor(p0, 8, 64); p1 += __shfl_xor(p1, 8, 64); p2 += __shfl_xor(p2, 8, 64);

    if (pub) {
      float hr = p0 + bh0, hz = p1 + bh1, hn = p2 + bh2;
      float rg = 1.f / (1.f + __expf(-(xr + hr)));
      float zg = 1.f / (1.f + __expf(-(xz + hz)));
      float e2 = __expf(2.f * (xn + rg * hn));
      float nn = 1.f - 2.f / (e2 + 1.f);   // tanh, saturates correctly
      float hnew = (1.f - zg) * nn + zg * ho;
      union { float f; unsigned u; } pv; pv.f = hnew;
      unsigned long long up = ((unsigned long long)(su + 1) << 32) |
                              (unsigned long long)pv.u;
      __hip_atomic_store(h_pairs + (size_t)((s + 1) & 1) * 512 + col, up,
                         __ATOMIC_RELAXED, __HIP_MEMORY_SCOPE_AGENT);
      out_gru[(size_t)s * H_DIM + col] = hnew;
      ho = hnew;
    }
  }
}

// ---------------- flashback window + SELU -> bf16 swizzled A ----------------
__global__ __launch_bounds__(256) void k_flash(const float* __restrict__ out_gru,
                                               const float* __restrict__ tim,
                                               const float* __restrict__ coord,
                                               unsigned short* __restrict__ hs_sw) {
  __shared__ float hsl[512];
  int s = blockIdx.x;
  int t = threadIdx.x;
  float w[WINN];
  float ts = tim[s];
  float cx = coord[s * 2], cy = coord[s * 2 + 1];
  float wsum = 0.f;
#pragma unroll
  for (int d = 0; d < WINN; ++d) {
    int j = s - d;
    float wd = 0.f;
    if (j >= 0) {
      float dt = ts - tim[j];
      float dx = cx - coord[j * 2], dy = cy - coord[j * 2 + 1];
      float sq = dx * dx + dy * dy;
      float ds = sq > 0.f ? sqrtf(sq) : 0.f;
      float ft = (cosf(dt * 7.2722052166430395e-05f) + 1.f) * 0.5f *
                 expf(dt * -1.1574074074074074e-06f);
      float fs = expf(-50.f * ds);
      wd = ft * fs + 1e-10f;
    }
    w[d] = wd;
    wsum += wd;
  }
  float inv = 1.f / wsum;
  for (int h = t; h < H_DIM; h += 256) {
    float a = 0.f;
#pragma unroll
    for (int d = 0; d < WINN; ++d) {
      int j = s - d;
      if (j >= 0) a += w[d] * out_gru[(size_t)j * H_DIM + h];
    }
    a *= inv;
    float o = a > 0.f ? 1.0507009873554805f * a
                      : 1.7580993408473766f * expm1f(a);  // lambda*alpha
    hsl[h] = o;
  }
  __syncthreads();
  if (t < 64) {
    int kt = t >> 2, q = t & 3;
    const float* p = &hsl[t * 8];
    u32x4 pk;
    pk.x = pack2(p[0], p[1]); pk.y = pack2(p[2], p[3]);
    pk.z = pack2(p[4], p[5]); pk.w = pack2(p[6], p[7]);
    int st = s >> 7, m = s & 127;
    int cd = st * 8192 + kt * 512 + q * 128 + m;
    *(u32x4*)(hs_sw + (size_t)cd * 8) = pk;
  }
}

// ---------------- y -= log(lse_sum[row]), in place, float4 ----------------
__global__ __launch_bounds__(256) void k_sub(float* __restrict__ Y,
                                             const float* __restrict__ lse) {
  int i = blockIdx.x * 256 + threadIdx.x;
  const int n4 = S_DIM * (V_DIM / 4);
  if (i >= n4) return;
  int row = (i * 4) / V_DIM;
  f32x4* Y4 = (f32x4*)Y;
  f32x4 v = Y4[i];
  float l = logf(lse[row]);
  v.x -= l; v.y -= l; v.z -= l; v.w -= l;
  Y4[i] = v;
}

extern "C" void kernel_launch(void* const* d_in, const int* in_sizes, int n_in,
                              void* d_out, int out_size, void* d_ws, size_t ws_size,
                              hipStream_t stream) {
  const int*   loc   = (const int*)d_in[0];
  const float* tim   = (const float*)d_in[1];
  const float* coord = (const float*)d_in[2];
  const float* emb   = (const float*)d_in[3];
  const float* W_ih  = (const float*)d_in[4];
  const float* W_hh  = (const float*)d_in[5];
  const float* b_ih  = (const float*)d_in[6];
  const float* b_hh  = (const float*)d_in[7];
  const float* fc_w  = (const float*)d_in[8];
  const float* fc_b  = (const float*)d_in[9];
  float* Y = (float*)d_out;

  char* w = (char*)d_ws;
  unsigned long long* h_pairs = (unsigned long long*)(w);   //   8 KB (2 x 512 x 8B tagged)
  float* lse     = (float*)(w + 8192);                      //   8 KB (exp-sum accumulators)
  float* xg      = (float*)(w + 16384);                     //  12 MB (2048x1536)
  float* out_gru = (float*)(w + 12599296);                  //   4 MB (2048x512)
  unsigned short* x_sw   = (unsigned short*)(w + 16793600); //   2 MB
  unsigned short* wih_sw = (unsigned short*)(w + 18890752); // 1.5 MB
  unsigned short* hs_sw  = (unsigned short*)(w + 20463616); //   2 MB
  unsigned short* fcw_sw = (unsigned short*)(w + 22560768); // 51.25 MB -> total ~70.4 MB

  k_zero<<<16, 256, 0, stream>>>((int*)w, 4096);            // h_pairs + lse
  k_swizzle<<<12512, 256, 0, stream>>>(fc_w, fcw_sw, 50000, 391 * 8192);
  k_swizzle<<<384, 256, 0, stream>>>(W_ih, wih_sw, 1536, 12 * 8192);
  k_gather<<<512, 256, 0, stream>>>(emb, loc, x_sw);
  dim3 gx(12, 16);
  k_gemm<<<gx, 256, 0, stream>>>(x_sw, wih_sw, b_ih, xg, 1536, 1536, nullptr);
  k_gru<<<GRU_G, 256, 0, stream>>>(W_hh, b_hh, xg, h_pairs, out_gru);
  k_flash<<<2048, 256, 0, stream>>>(out_gru, tim, coord, hs_sw);
  dim3 gy(391, 16);
  k_gemm<<<gy, 256, 0, stream>>>(hs_sw, fcw_sw, fc_b, Y, 50000, 50000, lse);
  k_sub<<<100000, 256, 0, stream>>>(Y, lse);
}